// Round 11
// baseline (193.603 us; speedup 1.0000x reference)
//
#include <hip/hip_runtime.h>
#include <math.h>

#define B_ 4
#define C_ 32
#define D_ 16
#define H_ 128
#define W_ 128
#define HW_ (H_*W_)
#define SP_ (D_*HW_)

// padded s layout: [B][2][D][H][PW], col = w + 2, w in [-2, 129] reflected
#define PW_ 136
#define PPL_ (H_*PW_)          // plane stride
#define PCH_ (D_*PPL_)         // channel (mean/max) stride
#define NPLANES (B_*D_)        // 64 (b,d) planes
#define CSTR 32                // counter stride in ints (128 B apart)

typedef float f32x4 __attribute__((ext_vector_type(4)));
typedef float f32x4u __attribute__((ext_vector_type(4), aligned(4)));

__device__ __forceinline__ int refl(int i, int n) {
    i = (i < 0) ? -i : i;
    i = (i >= n) ? (2*n - 2 - i) : i;
    return i;
}

__global__ void zero_cnt_kernel(int* __restrict__ cnt) {
    if (threadIdx.x < NPLANES) cnt[threadIdx.x * CSTR] = 0;
}

// Pass 0: combined stencil Wc[ci][od][oh][ow] (2x7x7x5)
__global__ void prep_weights_kernel(const float* __restrict__ w1,
                                    const float* __restrict__ w2,
                                    const float* __restrict__ w3,
                                    const float* __restrict__ wf,
                                    float* __restrict__ Wc) {
    int t = blockIdx.x * blockDim.x + threadIdx.x;
    if (t >= 2*7*7*5) return;
    int ow = t % 5;
    int oh = (t / 5) % 7;
    int od = (t / 35) % 7;
    int ci = t / 245;
    float v = wf[0] * w1[((ci*7+od)*7+oh)*5+ow];
    if (od>=1 && od<=5 && oh>=1 && oh<=5 && ow>=1 && ow<=3)
        v = fmaf(wf[1], w2[((ci*5+(od-1))*5+(oh-1))*3+(ow-1)], v);
    if (od>=2 && od<=4 && oh>=2 && oh<=4 && ow==2)
        v = fmaf(wf[2], w3[(ci*3+(od-2))*3+(oh-2)], v);
    Wc[t] = v;
}

// Fused pool->att kernel. Grid = 512 blocks (2/CU, all co-resident).
// Every block: (1) pool 1/8 of plane p=bid>>3 into padded s, publish;
//              (2) att tile abid=bid after acquire-waiting on its 8 planes.
// att cohort for batch b == pool cohort [128b,128b+128) => safe at >=1/CU.
__global__ __launch_bounds__(256, 2) void fused_kernel(
        const float* __restrict__ x,
        float* __restrict__ s,
        const float* __restrict__ Wc,
        float* __restrict__ out,
        int* __restrict__ cnt) {
    int bid = blockIdx.x;
    int t = threadIdx.x;

    // ---------------- pool phase ----------------
    {
        int p = bid >> 3;              // plane id = b*16 + d
        int pb = p >> 4, pd = p & 15;
        int h0b = (bid & 7) * 16;
        #pragma unroll
        for (int rep = 0; rep < 2; ++rep) {
            int it = t + rep*256;      // 512 items: 16 rows x 32 w-quads
            int w4 = (it & 31) * 4;
            int h  = h0b + (it >> 5);
            const float* xp = x + (pb*C_*D_ + pd)*HW_ + h*W_ + w4;
            f32x4 v = *(const f32x4*)xp;
            f32x4 sm = v, mx = v;
            #pragma unroll 8
            for (int c = 1; c < C_; ++c) {
                f32x4 u = *(const f32x4*)(xp + c*SP_);
                sm += u;
                mx.x=fmaxf(mx.x,u.x); mx.y=fmaxf(mx.y,u.y);
                mx.z=fmaxf(mx.z,u.z); mx.w=fmaxf(mx.w,u.w);
            }
            sm *= (1.0f/32.0f);
            float* rm = s + (pb*2+0)*PCH_ + pd*PPL_ + h*PW_;
            float* rM = s + (pb*2+1)*PCH_ + pd*PPL_ + h*PW_;
            *(f32x4u*)(rm + w4 + 2) = sm;
            *(f32x4u*)(rM + w4 + 2) = mx;
            if (w4 == 0) {              // cols 0,1 = w=-2,-1 -> refl 2,1
                rm[0] = sm.z; rm[1] = sm.y;
                rM[0] = mx.z; rM[1] = mx.y;
            } else if (w4 == 124) {     // cols 130,131 = w=128,129 -> refl 126,125
                rm[130] = sm.z; rm[131] = sm.y;
                rM[130] = mx.z; rM[131] = mx.y;
            }
        }
        __threadfence();               // all this thread's s-stores device-visible
        __syncthreads();               // whole block fenced
        if (t == 0)
            __hip_atomic_fetch_add(&cnt[p*CSTR], 1, __ATOMIC_RELEASE,
                                   __HIP_MEMORY_SCOPE_AGENT);
    }

    // ---------------- att phase ----------------
    int ht = bid & 15;
    int dp = (bid >> 4) & 7;
    int b  = bid >> 7;
    int w0 = (t & 31) * 4;
    int h0 = ht * 8 + (t >> 5);
    int d0 = dp * 2;

    int dpi[8];                        // plane indices refl(d0+k-3)
    #pragma unroll
    for (int k = 0; k < 8; ++k) dpi[k] = refl(d0 + k - 3, D_);

    // acquire-wait: 8 lanes poll 8 padded counters with atomic LOADS (no RMW)
    if (t < 8) {
        int pp = b*16 + dpi[t];
        while (__hip_atomic_load(&cnt[pp*CSTR], __ATOMIC_ACQUIRE,
                                 __HIP_MEMORY_SCOPE_AGENT) < 8)
            __builtin_amdgcn_s_sleep(2);
    }
    __syncthreads();
    __threadfence();                   // acquire fence for all threads

    float acc0[4] = {0.f, 0.f, 0.f, 0.f};
    float acc1[4] = {0.f, 0.f, 0.f, 0.f};

    for (int ci = 0; ci < 2; ++ci) {
        const float* sc = s + (b*2 + ci)*PCH_;
        const float* wcb_ci = Wc + ci*245;
        for (int oh = 0; oh < 7; ++oh) {
            const float* sh = sc + refl(h0 + oh - 3, H_)*PW_ + w0;
            const float* wcb = wcb_ci + oh*5;   // + od*35 + ow
            #pragma unroll
            for (int k = 0; k < 8; ++k) {
                const float* rp = sh + dpi[k]*PPL_;
                const f32x4 L = *(const f32x4*)(rp);
                const f32x4 R = *(const f32x4*)(rp + 4);
                float v[8] = {L.x, L.y, L.z, L.w, R.x, R.y, R.z, R.w};
                if (k <= 6) {                    // output d0: od = k
                    const float* wp = wcb + k*35;
                    #pragma unroll
                    for (int ow = 0; ow < 5; ++ow) {
                        float wgt = wp[ow];
                        #pragma unroll
                        for (int wi = 0; wi < 4; ++wi)
                            acc0[wi] = fmaf(wgt, v[wi+ow], acc0[wi]);
                    }
                }
                if (k >= 1) {                    // output d0+1: od = k-1
                    const float* wp = wcb + (k-1)*35;
                    #pragma unroll
                    for (int ow = 0; ow < 5; ++ow) {
                        float wgt = wp[ow];
                        #pragma unroll
                        for (int wi = 0; wi < 4; ++wi)
                            acc1[wi] = fmaf(wgt, v[wi+ow], acc1[wi]);
                    }
                }
            }
        }
    }

    float sg0[4], sg1[4];
    #pragma unroll
    for (int wi = 0; wi < 4; ++wi) {
        sg0[wi] = 1.0f/(1.0f + __expf(-acc0[wi]));
        sg1[wi] = 1.0f/(1.0f + __expf(-acc1[wi]));
    }

    int obase = (b*C_*D_ + d0)*HW_ + h0*W_ + w0;
    #pragma unroll 8
    for (int c = 0; c < C_; ++c) {
        int i0 = obase + c*SP_;
        f32x4 xv0 = *(const f32x4*)(x + i0);
        f32x4 xv1 = *(const f32x4*)(x + i0 + HW_);
        f32x4 o0; o0.x=xv0.x*sg0[0]; o0.y=xv0.y*sg0[1]; o0.z=xv0.z*sg0[2]; o0.w=xv0.w*sg0[3];
        f32x4 o1; o1.x=xv1.x*sg1[0]; o1.y=xv1.y*sg1[1]; o1.z=xv1.z*sg1[2]; o1.w=xv1.w*sg1[3];
        *(f32x4*)(out + i0) = o0;
        *(f32x4*)(out + i0 + HW_) = o1;
    }
}

extern "C" void kernel_launch(void* const* d_in, const int* in_sizes, int n_in,
                              void* d_out, int out_size, void* d_ws, size_t ws_size,
                              hipStream_t stream) {
    const float* x  = (const float*)d_in[0];
    const float* w1 = (const float*)d_in[1];
    const float* w2 = (const float*)d_in[2];
    const float* w3 = (const float*)d_in[3];
    const float* wf = (const float*)d_in[4];
    float* out = (float*)d_out;
    float* Wc = (float*)d_ws;                         // 512 floats
    float* s  = (float*)d_ws + 512;                   // padded s, 8.9 MB
    int*   cnt = (int*)(s + (size_t)B_*2*PCH_);       // 64 counters, 128 B apart

    zero_cnt_kernel<<<1, 64, 0, stream>>>(cnt);
    prep_weights_kernel<<<1, 512, 0, stream>>>(w1, w2, w3, wf, Wc);
    fused_kernel<<<512, 256, 0, stream>>>(x, s, Wc, out, cnt);
}

// Round 12
// 156.428 us; speedup vs baseline: 1.2376x; 1.2376x over previous
//
#include <hip/hip_runtime.h>
#include <hip/hip_cooperative_groups.h>
#include <math.h>

namespace cg = cooperative_groups;

#define B_ 4
#define C_ 32
#define D_ 16
#define H_ 128
#define W_ 128
#define HW_ (H_*W_)
#define SP_ (D_*HW_)

// padded s layout: [B][2][D][H][PW], col = w + 2, w in [-2, 129] reflected
#define PW_ 136
#define PPL_ (H_*PW_)          // plane stride
#define PCH_ (D_*PPL_)         // channel (mean/max) stride

typedef float f32x4 __attribute__((ext_vector_type(4)));
typedef float f32x4u __attribute__((ext_vector_type(4), aligned(4)));

__device__ __forceinline__ int refl(int i, int n) {
    i = (i < 0) ? -i : i;
    i = (i >= n) ? (2*n - 2 - i) : i;
    return i;
}

__device__ __forceinline__ void prep_one(int t, const float* __restrict__ w1,
                                         const float* __restrict__ w2,
                                         const float* __restrict__ w3,
                                         const float* __restrict__ wf,
                                         float* __restrict__ Wc) {
    int ow = t % 5;
    int oh = (t / 5) % 7;
    int od = (t / 35) % 7;
    int ci = t / 245;
    float v = wf[0] * w1[((ci*7+od)*7+oh)*5+ow];
    if (od>=1 && od<=5 && oh>=1 && oh<=5 && ow>=1 && ow<=3)
        v = fmaf(wf[1], w2[((ci*5+(od-1))*5+(oh-1))*3+(ow-1)], v);
    if (od>=2 && od<=4 && oh>=2 && oh<=4 && ow==2)
        v = fmaf(wf[2], w3[(ci*3+(od-2))*3+(oh-2)], v);
    Wc[t] = v;
}

__device__ __forceinline__ void pool_share(int bid, int t,
        const float* __restrict__ x, float* __restrict__ s) {
    int p = bid >> 3;              // plane id = b*16 + d
    int pb = p >> 4, pd = p & 15;
    int h0b = (bid & 7) * 16;
    #pragma unroll
    for (int rep = 0; rep < 2; ++rep) {
        int it = t + rep*256;      // 512 items: 16 rows x 32 w-quads
        int w4 = (it & 31) * 4;
        int h  = h0b + (it >> 5);
        const float* xp = x + (pb*C_*D_ + pd)*HW_ + h*W_ + w4;
        f32x4 v = *(const f32x4*)xp;
        f32x4 sm = v, mx = v;
        #pragma unroll 8
        for (int c = 1; c < C_; ++c) {
            f32x4 u = *(const f32x4*)(xp + c*SP_);
            sm += u;
            mx.x=fmaxf(mx.x,u.x); mx.y=fmaxf(mx.y,u.y);
            mx.z=fmaxf(mx.z,u.z); mx.w=fmaxf(mx.w,u.w);
        }
        sm *= (1.0f/32.0f);
        float* rm = s + (pb*2+0)*PCH_ + pd*PPL_ + h*PW_;
        float* rM = s + (pb*2+1)*PCH_ + pd*PPL_ + h*PW_;
        *(f32x4u*)(rm + w4 + 2) = sm;
        *(f32x4u*)(rM + w4 + 2) = mx;
        if (w4 == 0) {              // cols 0,1 = w=-2,-1 -> refl 2,1
            rm[0] = sm.z; rm[1] = sm.y;
            rM[0] = mx.z; rM[1] = mx.y;
        } else if (w4 == 124) {     // cols 130,131 = w=128,129 -> refl 126,125
            rm[130] = sm.z; rm[131] = sm.y;
            rM[130] = mx.z; rM[131] = mx.y;
        }
    }
}

__device__ __forceinline__ void att_tile(int abid, int t,
        const float* __restrict__ x, const float* __restrict__ s,
        const float* __restrict__ Wc, float* __restrict__ out) {
    int ht = abid & 15;
    int dp = (abid >> 4) & 7;
    int b  = abid >> 7;
    int w0 = (t & 31) * 4;
    int h0 = ht * 8 + (t >> 5);
    int d0 = dp * 2;

    int drow[8];
    #pragma unroll
    for (int k = 0; k < 8; ++k) drow[k] = refl(d0 + k - 3, D_) * PPL_;

    float acc0[4] = {0.f, 0.f, 0.f, 0.f};
    float acc1[4] = {0.f, 0.f, 0.f, 0.f};

    for (int ci = 0; ci < 2; ++ci) {
        const float* sc = s + (b*2 + ci)*PCH_;
        const float* wcb_ci = Wc + ci*245;
        for (int oh = 0; oh < 7; ++oh) {
            const float* sh = sc + refl(h0 + oh - 3, H_)*PW_ + w0;
            const float* wcb = wcb_ci + oh*5;   // + od*35 + ow
            #pragma unroll
            for (int k = 0; k < 8; ++k) {
                const float* rp = sh + drow[k];
                const f32x4 L = *(const f32x4*)(rp);
                const f32x4 R = *(const f32x4*)(rp + 4);
                float v[8] = {L.x, L.y, L.z, L.w, R.x, R.y, R.z, R.w};
                if (k <= 6) {                    // output d0: od = k
                    const float* wp = wcb + k*35;
                    #pragma unroll
                    for (int ow = 0; ow < 5; ++ow) {
                        float wgt = wp[ow];
                        #pragma unroll
                        for (int wi = 0; wi < 4; ++wi)
                            acc0[wi] = fmaf(wgt, v[wi+ow], acc0[wi]);
                    }
                }
                if (k >= 1) {                    // output d0+1: od = k-1
                    const float* wp = wcb + (k-1)*35;
                    #pragma unroll
                    for (int ow = 0; ow < 5; ++ow) {
                        float wgt = wp[ow];
                        #pragma unroll
                        for (int wi = 0; wi < 4; ++wi)
                            acc1[wi] = fmaf(wgt, v[wi+ow], acc1[wi]);
                    }
                }
            }
        }
    }

    float sg0[4], sg1[4];
    #pragma unroll
    for (int wi = 0; wi < 4; ++wi) {
        sg0[wi] = 1.0f/(1.0f + __expf(-acc0[wi]));
        sg1[wi] = 1.0f/(1.0f + __expf(-acc1[wi]));
    }

    int obase = (b*C_*D_ + d0)*HW_ + h0*W_ + w0;
    #pragma unroll 8
    for (int c = 0; c < C_; ++c) {
        int i0 = obase + c*SP_;
        f32x4 xv0 = *(const f32x4*)(x + i0);
        f32x4 xv1 = *(const f32x4*)(x + i0 + HW_);
        f32x4 o0; o0.x=xv0.x*sg0[0]; o0.y=xv0.y*sg0[1]; o0.z=xv0.z*sg0[2]; o0.w=xv0.w*sg0[3];
        f32x4 o1; o1.x=xv1.x*sg1[0]; o1.y=xv1.y*sg1[1]; o1.z=xv1.z*sg1[2]; o1.w=xv1.w*sg1[3];
        *(f32x4*)(out + i0) = o0;
        *(f32x4*)(out + i0 + HW_) = o1;
    }
}

// ---- Cooperative fused kernel: pool -> grid.sync -> att. Grid 512 x 256. ----
__global__ __launch_bounds__(256, 2) void fused_coop_kernel(
        const float* __restrict__ x,
        float* __restrict__ s,
        float* __restrict__ Wc,
        float* __restrict__ out,
        const float* __restrict__ w1,
        const float* __restrict__ w2,
        const float* __restrict__ w3,
        const float* __restrict__ wf) {
    int bid = blockIdx.x;
    int t = threadIdx.x;
    if (bid == 0) {
        if (t < 245) prep_one(t, w1, w2, w3, wf, Wc);
        int t2 = t + 245;
        if (t2 < 490) prep_one(t2, w1, w2, w3, wf, Wc);
    }
    pool_share(bid, t, x, s);
    cg::this_grid().sync();
    att_tile(bid, t, x, s, Wc, out);
}

// ---- Fallback split kernels (R10 path) ----
__global__ void prep_weights_kernel(const float* __restrict__ w1,
                                    const float* __restrict__ w2,
                                    const float* __restrict__ w3,
                                    const float* __restrict__ wf,
                                    float* __restrict__ Wc) {
    int t = blockIdx.x * blockDim.x + threadIdx.x;
    if (t < 2*7*7*5) prep_one(t, w1, w2, w3, wf, Wc);
}

__global__ __launch_bounds__(256) void pool_kernel(const float* __restrict__ x,
                                                   float* __restrict__ s) {
    int bid = blockIdx.x;
    if (bid < 512) pool_share(bid, threadIdx.x, x, s);
}

__global__ __launch_bounds__(256, 2) void spatial_att_kernel(
        const float* __restrict__ x,
        const float* __restrict__ s,
        const float* __restrict__ Wc,
        float* __restrict__ out) {
    att_tile(blockIdx.x, threadIdx.x, x, s, Wc, out);
}

extern "C" void kernel_launch(void* const* d_in, const int* in_sizes, int n_in,
                              void* d_out, int out_size, void* d_ws, size_t ws_size,
                              hipStream_t stream) {
    const float* x  = (const float*)d_in[0];
    const float* w1 = (const float*)d_in[1];
    const float* w2 = (const float*)d_in[2];
    const float* w3 = (const float*)d_in[3];
    const float* wf = (const float*)d_in[4];
    float* out = (float*)d_out;
    float* Wc = (float*)d_ws;            // 512 floats
    float* s  = (float*)d_ws + 512;      // padded [B][2][D][H][136] = 8.9 MB

    void* args[] = {(void*)&x, (void*)&s, (void*)&Wc, (void*)&out,
                    (void*)&w1, (void*)&w2, (void*)&w3, (void*)&wf};
    hipError_t err = hipLaunchCooperativeKernel((void*)fused_coop_kernel,
                                                dim3(512), dim3(256),
                                                args, 0, stream);
    if (err != hipSuccess) {
        // fallback: proven 3-kernel split path
        prep_weights_kernel<<<1, 512, 0, stream>>>(w1, w2, w3, wf, Wc);
        pool_kernel<<<512, 256, 0, stream>>>(x, s);
        spatial_att_kernel<<<B_*(D_/2)*(H_/8), 256, 0, stream>>>(x, s, Wc, out);
    }
}

// Round 13
// 92.741 us; speedup vs baseline: 2.0876x; 1.6867x over previous
//
#include <hip/hip_runtime.h>
#include <math.h>

#define B_ 4
#define C_ 32
#define D_ 16
#define H_ 128
#define W_ 128
#define HW_ (H_*W_)
#define SP_ (D_*HW_)

// padded s layout: [B][2][D][H][PW], col = w + 2, w in [-2, 129] reflected
#define PW_ 136
#define PPL_ (H_*PW_)          // plane stride
#define PCH_ (D_*PPL_)         // channel (mean/max) stride

typedef float f32x4 __attribute__((ext_vector_type(4)));
typedef float f32x4u __attribute__((ext_vector_type(4), aligned(4)));

__device__ __forceinline__ int refl(int i, int n) {
    i = (i < 0) ? -i : i;
    i = (i >= n) ? (2*n - 2 - i) : i;
    return i;
}

__device__ __forceinline__ void prep_one(int t, const float* __restrict__ w1,
                                         const float* __restrict__ w2,
                                         const float* __restrict__ w3,
                                         const float* __restrict__ wf,
                                         float* __restrict__ Wc) {
    int ow = t % 5;
    int oh = (t / 5) % 7;
    int od = (t / 35) % 7;
    int ci = t / 245;
    float v = wf[0] * w1[((ci*7+od)*7+oh)*5+ow];
    if (od>=1 && od<=5 && oh>=1 && oh<=5 && ow>=1 && ow<=3)
        v = fmaf(wf[1], w2[((ci*5+(od-1))*5+(oh-1))*3+(ow-1)], v);
    if (od>=2 && od<=4 && oh>=2 && oh<=4 && ow==2)
        v = fmaf(wf[2], w3[(ci*3+(od-2))*3+(oh-2)], v);
    Wc[t] = v;
}

// Pool slice kernel: 2 batches starting at b0. Grid 512 (+1 prep block for
// slice 0). Writes padded s (reflection-resolved columns).
__global__ __launch_bounds__(256) void pool_kernel(
        const float* __restrict__ x, float* __restrict__ s,
        const float* __restrict__ w1, const float* __restrict__ w2,
        const float* __restrict__ w3, const float* __restrict__ wf,
        float* __restrict__ Wc, int b0) {
    if (blockIdx.x >= 512) {           // prep block (only in slice-0's grid)
        int t = threadIdx.x;
        if (t < 245) prep_one(t, w1, w2, w3, wf, Wc);
        int t2 = t + 245;
        if (t2 < 490) prep_one(t2, w1, w2, w3, wf, Wc);
        return;
    }
    int idx = blockIdx.x * 256 + threadIdx.x;   // 2*16*128*32 = 131072 items
    int w4 = (idx & 31) * 4;
    int rest = idx >> 5;
    int h = rest & 127;
    int bd = rest >> 7;
    int d = bd & 15;
    int b = b0 + (bd >> 4);
    const float* xp = x + (b*C_*D_ + d)*HW_ + h*W_ + w4;
    f32x4 v = *(const f32x4*)xp;
    f32x4 sm = v, mx = v;
    #pragma unroll 8
    for (int c = 1; c < C_; ++c) {
        f32x4 u = *(const f32x4*)(xp + c*SP_);
        sm += u;
        mx.x=fmaxf(mx.x,u.x); mx.y=fmaxf(mx.y,u.y);
        mx.z=fmaxf(mx.z,u.z); mx.w=fmaxf(mx.w,u.w);
    }
    sm *= (1.0f/32.0f);
    float* rm = s + (b*2+0)*PCH_ + d*PPL_ + h*PW_;
    float* rM = s + (b*2+1)*PCH_ + d*PPL_ + h*PW_;
    *(f32x4u*)(rm + w4 + 2) = sm;
    *(f32x4u*)(rM + w4 + 2) = mx;
    if (w4 == 0) {              // cols 0,1 = w=-2,-1 -> refl 2,1
        rm[0] = sm.z; rm[1] = sm.y;
        rM[0] = mx.z; rM[1] = mx.y;
    } else if (w4 == 124) {     // cols 130,131 = w=128,129 -> refl 126,125
        rm[130] = sm.z; rm[131] = sm.y;
        rM[130] = mx.z; rM[131] = mx.y;
    }
}

// Att slice kernel: 2 batches starting at b0. Grid 256 = 2 x (D/2) x (H/8).
// Body identical to R10 (2d x 1h x 4w tile, aligned padded loads).
__global__ __launch_bounds__(256, 2) void spatial_att_kernel(
        const float* __restrict__ x,
        const float* __restrict__ s,
        const float* __restrict__ Wc,
        float* __restrict__ out, int b0) {
    int bid = blockIdx.x;
    int ht = bid & 15;
    int dp = (bid >> 4) & 7;
    int b  = b0 + (bid >> 7);
    int t = threadIdx.x;
    int w0 = (t & 31) * 4;
    int h0 = ht * 8 + (t >> 5);
    int d0 = dp * 2;

    int drow[8];
    #pragma unroll
    for (int k = 0; k < 8; ++k) drow[k] = refl(d0 + k - 3, D_) * PPL_;

    float acc0[4] = {0.f, 0.f, 0.f, 0.f};
    float acc1[4] = {0.f, 0.f, 0.f, 0.f};

    for (int ci = 0; ci < 2; ++ci) {
        const float* sc = s + (b*2 + ci)*PCH_;
        const float* wcb_ci = Wc + ci*245;
        for (int oh = 0; oh < 7; ++oh) {
            const float* sh = sc + refl(h0 + oh - 3, H_)*PW_ + w0;
            const float* wcb = wcb_ci + oh*5;   // + od*35 + ow
            #pragma unroll
            for (int k = 0; k < 8; ++k) {
                const float* rp = sh + drow[k];
                const f32x4 L = *(const f32x4*)(rp);
                const f32x4 R = *(const f32x4*)(rp + 4);
                float v[8] = {L.x, L.y, L.z, L.w, R.x, R.y, R.z, R.w};
                if (k <= 6) {                    // output d0: od = k
                    const float* wp = wcb + k*35;
                    #pragma unroll
                    for (int ow = 0; ow < 5; ++ow) {
                        float wgt = wp[ow];
                        #pragma unroll
                        for (int wi = 0; wi < 4; ++wi)
                            acc0[wi] = fmaf(wgt, v[wi+ow], acc0[wi]);
                    }
                }
                if (k >= 1) {                    // output d0+1: od = k-1
                    const float* wp = wcb + (k-1)*35;
                    #pragma unroll
                    for (int ow = 0; ow < 5; ++ow) {
                        float wgt = wp[ow];
                        #pragma unroll
                        for (int wi = 0; wi < 4; ++wi)
                            acc1[wi] = fmaf(wgt, v[wi+ow], acc1[wi]);
                    }
                }
            }
        }
    }

    float sg0[4], sg1[4];
    #pragma unroll
    for (int wi = 0; wi < 4; ++wi) {
        sg0[wi] = 1.0f/(1.0f + __expf(-acc0[wi]));
        sg1[wi] = 1.0f/(1.0f + __expf(-acc1[wi]));
    }

    int obase = (b*C_*D_ + d0)*HW_ + h0*W_ + w0;
    #pragma unroll 8
    for (int c = 0; c < C_; ++c) {
        int i0 = obase + c*SP_;
        f32x4 xv0 = *(const f32x4*)(x + i0);
        f32x4 xv1 = *(const f32x4*)(x + i0 + HW_);
        f32x4 o0; o0.x=xv0.x*sg0[0]; o0.y=xv0.y*sg0[1]; o0.z=xv0.z*sg0[2]; o0.w=xv0.w*sg0[3];
        f32x4 o1; o1.x=xv1.x*sg1[0]; o1.y=xv1.y*sg1[1]; o1.z=xv1.z*sg1[2]; o1.w=xv1.w*sg1[3];
        *(f32x4*)(out + i0) = o0;
        *(f32x4*)(out + i0 + HW_) = o1;
    }
}

extern "C" void kernel_launch(void* const* d_in, const int* in_sizes, int n_in,
                              void* d_out, int out_size, void* d_ws, size_t ws_size,
                              hipStream_t stream) {
    const float* x  = (const float*)d_in[0];
    const float* w1 = (const float*)d_in[1];
    const float* w2 = (const float*)d_in[2];
    const float* w3 = (const float*)d_in[3];
    const float* wf = (const float*)d_in[4];
    float* out = (float*)d_out;
    float* Wc = (float*)d_ws;            // 512 floats
    float* s  = (float*)d_ws + 512;      // padded [B][2][D][H][136] = 8.9 MB

    // Batch-halved pipeline: keeps each att slice's x-read inside the LLC
    // window warmed by its pool slice (67+67 MB << 256 MB).
    pool_kernel<<<513, 256, 0, stream>>>(x, s, w1, w2, w3, wf, Wc, 0);
    spatial_att_kernel<<<256, 256, 0, stream>>>(x, s, Wc, out, 0);
    pool_kernel<<<512, 256, 0, stream>>>(x, s, w1, w2, w3, wf, Wc, 2);
    spatial_att_kernel<<<256, 256, 0, stream>>>(x, s, Wc, out, 2);
}

// Round 14
// 85.151 us; speedup vs baseline: 2.2736x; 1.0891x over previous
//
#include <hip/hip_runtime.h>
#include <math.h>

#define B_ 4
#define C_ 32
#define D_ 16
#define H_ 128
#define W_ 128
#define HW_ (H_*W_)
#define SP_ (D_*HW_)

// padded s layout: [B][2][D][H][PW], col = w + 2, w in [-2, 129] reflected
#define PW_ 136
#define PPL_ (H_*PW_)          // plane stride
#define PCH_ (D_*PPL_)         // channel (mean/max) stride

typedef float f32x4 __attribute__((ext_vector_type(4)));
typedef float f32x4u __attribute__((ext_vector_type(4), aligned(4)));

__device__ __forceinline__ int refl(int i, int n) {
    i = (i < 0) ? -i : i;
    i = (i >= n) ? (2*n - 2 - i) : i;
    return i;
}

__device__ __forceinline__ void prep_one(int t, const float* __restrict__ w1,
                                         const float* __restrict__ w2,
                                         const float* __restrict__ w3,
                                         const float* __restrict__ wf,
                                         float* __restrict__ Wc) {
    int ow = t % 5;
    int oh = (t / 5) % 7;
    int od = (t / 35) % 7;
    int ci = t / 245;
    float v = wf[0] * w1[((ci*7+od)*7+oh)*5+ow];
    if (od>=1 && od<=5 && oh>=1 && oh<=5 && ow>=1 && ow<=3)
        v = fmaf(wf[1], w2[((ci*5+(od-1))*5+(oh-1))*3+(ow-1)], v);
    if (od>=2 && od<=4 && oh>=2 && oh<=4 && ow==2)
        v = fmaf(wf[2], w3[(ci*3+(od-2))*3+(oh-2)], v);
    Wc[t] = v;
}

// Pool (all 4 batches) + prep block. Grid 1025: block 1024 builds Wc.
__global__ __launch_bounds__(256) void pool_kernel(
        const float* __restrict__ x, float* __restrict__ s,
        const float* __restrict__ w1, const float* __restrict__ w2,
        const float* __restrict__ w3, const float* __restrict__ wf,
        float* __restrict__ Wc) {
    if (blockIdx.x >= 1024) {          // prep block
        int t = threadIdx.x;
        if (t < 245) prep_one(t, w1, w2, w3, wf, Wc);
        int t2 = t + 245;
        if (t2 < 490) prep_one(t2, w1, w2, w3, wf, Wc);
        return;
    }
    int idx = blockIdx.x * 256 + threadIdx.x;   // 4*16*128*32 = 262144 items
    int w4 = (idx & 31) * 4;
    int rest = idx >> 5;
    int h = rest & 127;
    int bd = rest >> 7;
    int d = bd & 15;
    int b = bd >> 4;
    const float* xp = x + (b*C_*D_ + d)*HW_ + h*W_ + w4;
    f32x4 v = *(const f32x4*)xp;
    f32x4 sm = v, mx = v;
    #pragma unroll 8
    for (int c = 1; c < C_; ++c) {
        f32x4 u = *(const f32x4*)(xp + c*SP_);
        sm += u;
        mx.x=fmaxf(mx.x,u.x); mx.y=fmaxf(mx.y,u.y);
        mx.z=fmaxf(mx.z,u.z); mx.w=fmaxf(mx.w,u.w);
    }
    sm *= (1.0f/32.0f);
    float* rm = s + (b*2+0)*PCH_ + d*PPL_ + h*PW_;
    float* rM = s + (b*2+1)*PCH_ + d*PPL_ + h*PW_;
    *(f32x4u*)(rm + w4 + 2) = sm;
    *(f32x4u*)(rM + w4 + 2) = mx;
    if (w4 == 0) {              // cols 0,1 = w=-2,-1 -> refl 2,1
        rm[0] = sm.z; rm[1] = sm.y;
        rM[0] = mx.z; rM[1] = mx.y;
    } else if (w4 == 124) {     // cols 130,131 = w=128,129 -> refl 126,125
        rm[130] = sm.z; rm[131] = sm.y;
        rM[130] = mx.z; rM[131] = mx.y;
    }
}

// Att: 2x7x7x5 stencil on padded s + sigmoid + x-multiply.
// Thread tile: 1 d x 1 h x 4 w (acc = 4 regs). Block 256 = 32 w-tiles x 8 h.
// Grid: B*D*(H/8) = 1024; __launch_bounds__(256,4) -> 4 blocks/CU co-resident
// so stencil (latency) and epilogue (stream) phases of different blocks
// overlap on each CU.
__global__ __launch_bounds__(256, 4) void spatial_att_kernel(
        const float* __restrict__ x,
        const float* __restrict__ s,
        const float* __restrict__ Wc,
        float* __restrict__ out) {
    int bid = blockIdx.x;
    int ht = bid & 15;
    int d0 = (bid >> 4) & 15;
    int b  = bid >> 8;
    int t = threadIdx.x;
    int w0 = (t & 31) * 4;
    int h0 = ht * 8 + (t >> 5);

    int drow[7];
    #pragma unroll
    for (int k = 0; k < 7; ++k) drow[k] = refl(d0 + k - 3, D_) * PPL_;

    float acc[4] = {0.f, 0.f, 0.f, 0.f};

    for (int ci = 0; ci < 2; ++ci) {
        const float* sc = s + (b*2 + ci)*PCH_;
        const float* wcb_ci = Wc + ci*245;
        for (int oh = 0; oh < 7; ++oh) {
            const float* sh = sc + refl(h0 + oh - 3, H_)*PW_ + w0;
            const float* wcb = wcb_ci + oh*5;   // + od*35 + ow
            #pragma unroll
            for (int k = 0; k < 7; ++k) {
                const float* rp = sh + drow[k];
                const f32x4 L = *(const f32x4*)(rp);
                const f32x4 R = *(const f32x4*)(rp + 4);
                float v[8] = {L.x, L.y, L.z, L.w, R.x, R.y, R.z, R.w};
                const float* wp = wcb + k*35;
                #pragma unroll
                for (int ow = 0; ow < 5; ++ow) {
                    float wgt = wp[ow];
                    #pragma unroll
                    for (int wi = 0; wi < 4; ++wi)
                        acc[wi] = fmaf(wgt, v[wi+ow], acc[wi]);
                }
            }
        }
    }

    float sg[4];
    #pragma unroll
    for (int wi = 0; wi < 4; ++wi)
        sg[wi] = 1.0f/(1.0f + __expf(-acc[wi]));

    int obase = (b*C_*D_ + d0)*HW_ + h0*W_ + w0;
    #pragma unroll 8
    for (int c = 0; c < C_; ++c) {
        int i0 = obase + c*SP_;
        f32x4 xv = *(const f32x4*)(x + i0);
        f32x4 o; o.x=xv.x*sg[0]; o.y=xv.y*sg[1]; o.z=xv.z*sg[2]; o.w=xv.w*sg[3];
        *(f32x4*)(out + i0) = o;
    }
}

extern "C" void kernel_launch(void* const* d_in, const int* in_sizes, int n_in,
                              void* d_out, int out_size, void* d_ws, size_t ws_size,
                              hipStream_t stream) {
    const float* x  = (const float*)d_in[0];
    const float* w1 = (const float*)d_in[1];
    const float* w2 = (const float*)d_in[2];
    const float* w3 = (const float*)d_in[3];
    const float* wf = (const float*)d_in[4];
    float* out = (float*)d_out;
    float* Wc = (float*)d_ws;            // 512 floats
    float* s  = (float*)d_ws + 512;      // padded [B][2][D][H][136] = 8.9 MB

    pool_kernel<<<1025, 256, 0, stream>>>(x, s, w1, w2, w3, wf, Wc);
    spatial_att_kernel<<<B_*D_*(H_/8), 256, 0, stream>>>(x, s, Wc, out);
}

// Round 15
// 84.567 us; speedup vs baseline: 2.2893x; 1.0069x over previous
//
#include <hip/hip_runtime.h>
#include <math.h>

#define B_ 4
#define C_ 32
#define D_ 16
#define H_ 128
#define W_ 128
#define HW_ (H_*W_)
#define SP_ (D_*HW_)

// padded s layout: [B][2][D][H][PW], col = w + 2, w in [-2, 129] reflected
#define PW_ 136
#define PPL_ (H_*PW_)          // plane stride
#define PCH_ (D_*PPL_)         // channel (mean/max) stride

typedef float f32x4 __attribute__((ext_vector_type(4)));
typedef float f32x4u __attribute__((ext_vector_type(4), aligned(4)));

__device__ __forceinline__ int refl(int i, int n) {
    i = (i < 0) ? -i : i;
    i = (i >= n) ? (2*n - 2 - i) : i;
    return i;
}

__device__ __forceinline__ void prep_one(int t, const float* __restrict__ w1,
                                         const float* __restrict__ w2,
                                         const float* __restrict__ w3,
                                         const float* __restrict__ wf,
                                         float* __restrict__ Wc) {
    int ow = t % 5;
    int oh = (t / 5) % 7;
    int od = (t / 35) % 7;
    int ci = t / 245;
    float v = wf[0] * w1[((ci*7+od)*7+oh)*5+ow];
    if (od>=1 && od<=5 && oh>=1 && oh<=5 && ow>=1 && ow<=3)
        v = fmaf(wf[1], w2[((ci*5+(od-1))*5+(oh-1))*3+(ow-1)], v);
    if (od>=2 && od<=4 && oh>=2 && oh<=4 && ow==2)
        v = fmaf(wf[2], w3[(ci*3+(od-2))*3+(oh-2)], v);
    Wc[t] = v;
}

// Pool (all 4 batches) + prep block. Grid 1025: block 1024 builds Wc.
// Sweeps x in ascending (b,d,h) order.
__global__ __launch_bounds__(256) void pool_kernel(
        const float* __restrict__ x, float* __restrict__ s,
        const float* __restrict__ w1, const float* __restrict__ w2,
        const float* __restrict__ w3, const float* __restrict__ wf,
        float* __restrict__ Wc) {
    if (blockIdx.x >= 1024) {          // prep block
        int t = threadIdx.x;
        if (t < 245) prep_one(t, w1, w2, w3, wf, Wc);
        int t2 = t + 245;
        if (t2 < 490) prep_one(t2, w1, w2, w3, wf, Wc);
        return;
    }
    int idx = blockIdx.x * 256 + threadIdx.x;   // 4*16*128*32 = 262144 items
    int w4 = (idx & 31) * 4;
    int rest = idx >> 5;
    int h = rest & 127;
    int bd = rest >> 7;
    int d = bd & 15;
    int b = bd >> 4;
    const float* xp = x + (b*C_*D_ + d)*HW_ + h*W_ + w4;
    f32x4 v = *(const f32x4*)xp;
    f32x4 sm = v, mx = v;
    #pragma unroll 8
    for (int c = 1; c < C_; ++c) {
        f32x4 u = *(const f32x4*)(xp + c*SP_);
        sm += u;
        mx.x=fmaxf(mx.x,u.x); mx.y=fmaxf(mx.y,u.y);
        mx.z=fmaxf(mx.z,u.z); mx.w=fmaxf(mx.w,u.w);
    }
    sm *= (1.0f/32.0f);
    float* rm = s + (b*2+0)*PCH_ + d*PPL_ + h*PW_;
    float* rM = s + (b*2+1)*PCH_ + d*PPL_ + h*PW_;
    *(f32x4u*)(rm + w4 + 2) = sm;
    *(f32x4u*)(rM + w4 + 2) = mx;
    if (w4 == 0) {              // cols 0,1 = w=-2,-1 -> refl 2,1
        rm[0] = sm.z; rm[1] = sm.y;
        rM[0] = mx.z; rM[1] = mx.y;
    } else if (w4 == 124) {     // cols 130,131 = w=128,129 -> refl 126,125
        rm[130] = sm.z; rm[131] = sm.y;
        rM[130] = mx.z; rM[131] = mx.y;
    }
}

// Att: 2x7x7x5 stencil on padded s + sigmoid + x-multiply.
// Thread tile: 1 d x 1 h x 4 w. Block 256 = 32 w-tiles x 8 h. Grid 1024.
// DISPATCH REVERSED vs pool's sweep (anti-LRU): first att blocks touch the
// planes pool read last (LLC-hot). NT stores keep the out-stream from
// evicting x lines the reversed sweep will need.
__global__ __launch_bounds__(256, 4) void spatial_att_kernel(
        const float* __restrict__ x,
        const float* __restrict__ s,
        const float* __restrict__ Wc,
        float* __restrict__ out) {
    int bid = 1023 - blockIdx.x;       // reverse sweep
    int ht = bid & 15;
    int d0 = (bid >> 4) & 15;
    int b  = bid >> 8;
    int t = threadIdx.x;
    int w0 = (t & 31) * 4;
    int h0 = ht * 8 + (t >> 5);

    int drow[7];
    #pragma unroll
    for (int k = 0; k < 7; ++k) drow[k] = refl(d0 + k - 3, D_) * PPL_;

    float acc[4] = {0.f, 0.f, 0.f, 0.f};

    for (int ci = 0; ci < 2; ++ci) {
        const float* sc = s + (b*2 + ci)*PCH_;
        const float* wcb_ci = Wc + ci*245;
        for (int oh = 0; oh < 7; ++oh) {
            const float* sh = sc + refl(h0 + oh - 3, H_)*PW_ + w0;
            const float* wcb = wcb_ci + oh*5;   // + od*35 + ow
            #pragma unroll
            for (int k = 0; k < 7; ++k) {
                const float* rp = sh + drow[k];
                const f32x4 L = *(const f32x4*)(rp);
                const f32x4 R = *(const f32x4*)(rp + 4);
                float v[8] = {L.x, L.y, L.z, L.w, R.x, R.y, R.z, R.w};
                const float* wp = wcb + k*35;
                #pragma unroll
                for (int ow = 0; ow < 5; ++ow) {
                    float wgt = wp[ow];
                    #pragma unroll
                    for (int wi = 0; wi < 4; ++wi)
                        acc[wi] = fmaf(wgt, v[wi+ow], acc[wi]);
                }
            }
        }
    }

    float sg[4];
    #pragma unroll
    for (int wi = 0; wi < 4; ++wi)
        sg[wi] = 1.0f/(1.0f + __expf(-acc[wi]));

    int obase = (b*C_*D_ + d0)*HW_ + h0*W_ + w0;
    #pragma unroll 8
    for (int c = 0; c < C_; ++c) {
        int i0 = obase + c*SP_;
        f32x4 xv = *(const f32x4*)(x + i0);
        f32x4 o; o.x=xv.x*sg[0]; o.y=xv.y*sg[1]; o.z=xv.z*sg[2]; o.w=xv.w*sg[3];
        __builtin_nontemporal_store(o, (f32x4*)(out + i0));
    }
}

extern "C" void kernel_launch(void* const* d_in, const int* in_sizes, int n_in,
                              void* d_out, int out_size, void* d_ws, size_t ws_size,
                              hipStream_t stream) {
    const float* x  = (const float*)d_in[0];
    const float* w1 = (const float*)d_in[1];
    const float* w2 = (const float*)d_in[2];
    const float* w3 = (const float*)d_in[3];
    const float* wf = (const float*)d_in[4];
    float* out = (float*)d_out;
    float* Wc = (float*)d_ws;            // 512 floats
    float* s  = (float*)d_ws + 512;      // padded [B][2][D][H][136] = 8.9 MB

    pool_kernel<<<1025, 256, 0, stream>>>(x, s, w1, w2, w3, wf, Wc);
    spatial_att_kernel<<<B_*D_*(H_/8), 256, 0, stream>>>(x, s, Wc, out);
}